// Round 8
// baseline (326.515 us; speedup 1.0000x reference)
//
#include <hip/hip_runtime.h>
#include <hip/hip_bf16.h>

// GIN GNN forward, R8.
// KEY CHANGE: BN-stats atomics eliminated. Previous agg did 12500 blocks x
// 128 device atomics = 1.6M atomics/layer -> atomic-fabric serialized
// (R3's count_kernel measured this fabric: 1.6M atomics = 75us, all pipes
// idle). Now: 3125 blocks x 4 node-quads, stats in registers, ONE dense
// 512B partial store per block; redfin kernel reduces partials + BN affine.
// Slot rows + degs for all 4 quads preloaded (independent VMEM).

#define NN 50000
#define NE 800000
#define FD 64
#define NG 256
#define CAP 64            // slots per node == wave width; max degree ~42
#define NBLK 3125         // agg blocks; 4 waves x 4 quads = 16 nodes/block
#define BN_EPS 1e-5f

// ---------------- slot-table build ----------------

__global__ __launch_bounds__(256) void build_slots_kernel(
    const int* __restrict__ src, const int* __restrict__ dst,
    const float* __restrict__ ew, int* __restrict__ cursor,
    uint2* __restrict__ slots)
{
    int e = blockIdx.x * 256 + threadIdx.x;
    if (e < NE) {
        int d = dst[e];
        int pos = atomicAdd(&cursor[d], 1) & (CAP - 1);
        slots[(size_t)d * CAP + pos] = make_uint2((unsigned)src[e],
                                                  __float_as_uint(ew[e]));
    }
}

// ---------------- fused layer ----------------
// 1 node per wave per quad-iteration; lane = (g = edge group, l = feat quad).
// hin = af (.) (y[node] + sum_e w*y[src]) + cf * (1 + sum_e w)
// y = [relu]( hin @ W + b ); per-block BN partial sums via plain stores.
__global__ __launch_bounds__(256) void agg_layer_kernel(
    const float* __restrict__ h, const int* __restrict__ deg,
    const uint2* __restrict__ slots, const float* __restrict__ affine,
    const float* __restrict__ W, const float* __restrict__ b,
    float* __restrict__ y, float* __restrict__ partial, int relu_flag)
{
    __shared__ float Ws[FD * FD];       // 16 KB
    __shared__ float ps1[4][FD];
    __shared__ float ps2[4][FD];
    int tid  = threadIdx.x;
    int wave = tid >> 6, lane = tid & 63;
    int g = lane >> 4, l = lane & 15;

    // stage W into LDS (coalesced float4)
    {
        float4* Wv = (float4*)Ws;
        const float4* Wg = (const float4*)W;
        #pragma unroll
        for (int i = 0; i < 4; i++) Wv[tid + 256 * i] = Wg[tid + 256 * i];
    }

    const float4* __restrict__ h4 = (const float4*)h;

    // preload degs + slot rows for all 4 quads (independent VMEM, in flight
    // together -> no serial deg->slots->gather chain across iterations)
    int nodes[4], dgs[4];
    uint2 mss[4];
    #pragma unroll
    for (int k = 0; k < 4; k++) {
        nodes[k] = (k * NBLK + blockIdx.x) * 4 + wave;   // covers [0, NN)
        dgs[k] = deg[nodes[k]];
    }
    #pragma unroll
    for (int k = 0; k < 4; k++)
        mss[k] = slots[(size_t)nodes[k] * CAP + lane];   // lane i = entry i

    float4 af = make_float4(1.f, 1.f, 1.f, 1.f);
    float4 cf = make_float4(0.f, 0.f, 0.f, 0.f);
    if (affine) {
        af = ((const float4*)affine)[l];
        cf = ((const float4*)(affine + FD))[l];
    }
    float4 bias = ((const float4*)b)[l];

    __syncthreads();

    const float4* __restrict__ WsV = (const float4*)Ws;
    float4 s1 = make_float4(0.f, 0.f, 0.f, 0.f);   // BN stats accumulators
    float4 s2 = make_float4(0.f, 0.f, 0.f, 0.f);

    #pragma unroll
    for (int k = 0; k < 4; k++) {
        int node = nodes[k];
        int dg = dgs[k] > CAP ? CAP : dgs[k];       // wave-uniform
        uint2 ms = mss[k];
        float4 self = h4[(size_t)node * 16 + l];

        float4 acc = make_float4(0.f, 0.f, 0.f, 0.f);
        float wsum = 0.f;
        int nIter = (dg + 7) >> 3;                  // WAVE-UNIFORM trip count
        for (int i = 0; i < nIter; i++) {
            int e0 = 8 * i + g;
            int e1 = e0 + 4;
            int ee0 = (e0 < dg) ? e0 : 0;           // clamp to valid lane
            int ee1 = (e1 < dg) ? e1 : 0;
            int   sA = __shfl((int)ms.x, ee0, 64);
            int   sB = __shfl((int)ms.x, ee1, 64);
            float w0 = __uint_as_float((unsigned)__shfl((int)ms.y, ee0, 64));
            float w1 = __uint_as_float((unsigned)__shfl((int)ms.y, ee1, 64));
            w0 = (e0 < dg) ? w0 : 0.f;              // mask invalid entries
            w1 = (e1 < dg) ? w1 : 0.f;
            float4 v0 = h4[(size_t)sA * 16 + l];
            float4 v1 = h4[(size_t)sB * 16 + l];
            wsum += w0 + w1;
            acc.x = fmaf(w0, v0.x, acc.x); acc.y = fmaf(w0, v0.y, acc.y);
            acc.z = fmaf(w0, v0.z, acc.z); acc.w = fmaf(w0, v0.w, acc.w);
            acc.x = fmaf(w1, v1.x, acc.x); acc.y = fmaf(w1, v1.y, acc.y);
            acc.z = fmaf(w1, v1.z, acc.z); acc.w = fmaf(w1, v1.w, acc.w);
        }
        // reduce across the 4 edge groups -> replicated in all lanes
        acc.x += __shfl_xor(acc.x, 16, 64); acc.y += __shfl_xor(acc.y, 16, 64);
        acc.z += __shfl_xor(acc.z, 16, 64); acc.w += __shfl_xor(acc.w, 16, 64);
        wsum  += __shfl_xor(wsum, 16, 64);
        acc.x += __shfl_xor(acc.x, 32, 64); acc.y += __shfl_xor(acc.y, 32, 64);
        acc.z += __shfl_xor(acc.z, 32, 64); acc.w += __shfl_xor(acc.w, 32, 64);
        wsum  += __shfl_xor(wsum, 32, 64);

        float4 raw;
        raw.x = self.x + acc.x; raw.y = self.y + acc.y;
        raw.z = self.z + acc.z; raw.w = self.w + acc.w;

        float sw = 1.0f + wsum;
        float4 hin;
        hin.x = fmaf(af.x, raw.x, cf.x * sw);
        hin.y = fmaf(af.y, raw.y, cf.y * sw);
        hin.z = fmaf(af.z, raw.z, cf.z * sw);
        hin.w = fmaf(af.w, raw.w, cf.w * sw);

        // matvec: group g covers rows k in [16g, 16g+16) of W (from LDS)
        float4 yp = make_float4(0.f, 0.f, 0.f, 0.f);
        #pragma unroll
        for (int kk = 0; kk < 4; kk++) {
            int srcl = 4 * g + kk;      // lane holding features 4*srcl..+3
            float a0 = __shfl(hin.x, srcl, 64);
            float a1 = __shfl(hin.y, srcl, 64);
            float a2 = __shfl(hin.z, srcl, 64);
            float a3 = __shfl(hin.w, srcl, 64);
            int k0 = 16 * g + 4 * kk;
            float4 w0 = WsV[(k0 + 0) * 16 + l];
            float4 w1 = WsV[(k0 + 1) * 16 + l];
            float4 w2 = WsV[(k0 + 2) * 16 + l];
            float4 w3 = WsV[(k0 + 3) * 16 + l];
            yp.x = fmaf(a0, w0.x, yp.x); yp.y = fmaf(a0, w0.y, yp.y);
            yp.z = fmaf(a0, w0.z, yp.z); yp.w = fmaf(a0, w0.w, yp.w);
            yp.x = fmaf(a1, w1.x, yp.x); yp.y = fmaf(a1, w1.y, yp.y);
            yp.z = fmaf(a1, w1.z, yp.z); yp.w = fmaf(a1, w1.w, yp.w);
            yp.x = fmaf(a2, w2.x, yp.x); yp.y = fmaf(a2, w2.y, yp.y);
            yp.z = fmaf(a2, w2.z, yp.z); yp.w = fmaf(a2, w2.w, yp.w);
            yp.x = fmaf(a3, w3.x, yp.x); yp.y = fmaf(a3, w3.y, yp.y);
            yp.z = fmaf(a3, w3.z, yp.z); yp.w = fmaf(a3, w3.w, yp.w);
        }
        yp.x += __shfl_xor(yp.x, 16, 64); yp.y += __shfl_xor(yp.y, 16, 64);
        yp.z += __shfl_xor(yp.z, 16, 64); yp.w += __shfl_xor(yp.w, 16, 64);
        yp.x += __shfl_xor(yp.x, 32, 64); yp.y += __shfl_xor(yp.y, 32, 64);
        yp.z += __shfl_xor(yp.z, 32, 64); yp.w += __shfl_xor(yp.w, 32, 64);

        float4 yv;
        yv.x = yp.x + bias.x; yv.y = yp.y + bias.y;
        yv.z = yp.z + bias.z; yv.w = yp.w + bias.w;
        if (relu_flag) {
            yv.x = fmaxf(yv.x, 0.f); yv.y = fmaxf(yv.y, 0.f);
            yv.z = fmaxf(yv.z, 0.f); yv.w = fmaxf(yv.w, 0.f);
        }
        if (g == 0)
            ((float4*)y)[(size_t)node * 16 + l] = yv;
        // yv replicated across groups: accumulate stats (use g==0 copy later)
        s1.x += yv.x; s1.y += yv.y; s1.z += yv.z; s1.w += yv.w;
        s2.x = fmaf(yv.x, yv.x, s2.x); s2.y = fmaf(yv.y, yv.y, s2.y);
        s2.z = fmaf(yv.z, yv.z, s2.z); s2.w = fmaf(yv.w, yv.w, s2.w);
    }

    if (g == 0) {
        ((float4*)&ps1[wave][0])[l] = s1;
        ((float4*)&ps2[wave][0])[l] = s2;
    }
    __syncthreads();
    if (tid < FD) {
        float a = ps1[0][tid] + ps1[1][tid] + ps1[2][tid] + ps1[3][tid];
        float q = ps2[0][tid] + ps2[1][tid] + ps2[2][tid] + ps2[3][tid];
        partial[(size_t)blockIdx.x * 128 + tid]      = a;   // plain stores,
        partial[(size_t)blockIdx.x * 128 + 64 + tid] = q;   // NO atomics
    }
}

// ---------------- partial reduction + BN affine ----------------
// 64 blocks; block B reduces columns B (S1) and 64+B (S2) over 3125 rows.
__global__ __launch_bounds__(256) void redfin_kernel(
    const float* __restrict__ partial, const float* __restrict__ gamma,
    const float* __restrict__ beta, float* __restrict__ affine)
{
    __shared__ float red[256];
    int tid = threadIdx.x;
    int B = blockIdx.x;
    int half = tid >> 7;                // 0 -> S1 col, 1 -> S2 col
    int t = tid & 127;
    int f = B + half * 64;
    float s = 0.f;
    for (int j = t; j < NBLK; j += 128) s += partial[(size_t)j * 128 + f];
    red[tid] = s;
    __syncthreads();
    for (int off = 64; off >= 1; off >>= 1) {
        if ((tid & 127) < off) red[tid] += red[tid + off];
        __syncthreads();
    }
    if (tid == 0) {
        float S1 = red[0], S2 = red[128];
        float mu  = S1 * (1.f / NN);
        float var = S2 * (1.f / NN) - mu * mu;
        float a = gamma[B] * rsqrtf(var + BN_EPS);
        affine[B]      = a;
        affine[FD + B] = beta[B] - mu * a;
    }
}

// ---------------- fused pool + head ----------------
__global__ __launch_bounds__(256) void pool_head_kernel(
    const float* __restrict__ y, const int* __restrict__ batch,
    const float* __restrict__ affine3,
    const float* __restrict__ fcW1, const float* __restrict__ fcb1,
    const float* __restrict__ fcW2, const float* __restrict__ fcb2,
    float* __restrict__ out)
{
    __shared__ float red[16][FD];
    __shared__ int bounds[2];
    int tid = threadIdx.x;
    int g = blockIdx.x;
    if (tid < 2) {
        int target = g + tid;           // lower_bound(batch, target)
        int lo = 0, hi = NN;
        while (lo < hi) {
            int mid = (lo + hi) >> 1;
            if (batch[mid] < target) lo = mid + 1; else hi = mid;
        }
        bounds[tid] = lo;
    }
    __syncthreads();
    int s = bounds[0], e = bounds[1];
    int l = tid & 15, r = tid >> 4;
    const float4* __restrict__ y4 = (const float4*)y;
    float4 acc = make_float4(0.f, 0.f, 0.f, 0.f);
    for (int n = s + r; n < e; n += 16) {
        float4 v = y4[(size_t)n * 16 + l];
        acc.x += v.x; acc.y += v.y; acc.z += v.z; acc.w += v.w;
    }
    ((float4*)&red[r][0])[l] = acc;
    __syncthreads();
    for (int off = 8; off > 0; off >>= 1) {
        if (r < off) {
            float4 a = ((float4*)&red[r][0])[l];
            float4 o = ((float4*)&red[r + off][0])[l];
            a.x += o.x; a.y += o.y; a.z += o.z; a.w += o.w;
            ((float4*)&red[r][0])[l] = a;
        }
        __syncthreads();
    }
    if (tid < 64) {                      // wave-uniform branch: shuffles safe
        float cnt = (float)(e - s);
        float p = red[0][tid];
        p = fmaf(affine3[tid], p, affine3[FD + tid] * cnt);  // BN3
        p = fmaxf(p, 0.f);
        float acc1 = fcb1[tid];
        #pragma unroll
        for (int k = 0; k < FD; k++) {
            float pk = __shfl(p, k, 64);
            acc1 = fmaf(pk, fcW1[k * FD + tid], acc1);
        }
        acc1 = fmaxf(acc1, 0.f);
        float prod = acc1 * fcW2[tid];
        #pragma unroll
        for (int off = 32; off > 0; off >>= 1)
            prod += __shfl_xor(prod, off, 64);
        if (tid == 0) out[g] = prod + fcb2[0];
    }
}

extern "C" void kernel_launch(void* const* d_in, const int* in_sizes, int n_in,
                              void* d_out, int out_size, void* d_ws, size_t ws_size,
                              hipStream_t stream) {
    const float* x     = (const float*)d_in[0];
    const int*   ei    = (const int*)d_in[1];
    const float* ew    = (const float*)d_in[2];
    const int*   batch = (const int*)d_in[3];
    const float* W1 = (const float*)d_in[4],  *b1 = (const float*)d_in[5];
    const float* W2 = (const float*)d_in[6],  *b2 = (const float*)d_in[7];
    const float* W3 = (const float*)d_in[8],  *b3 = (const float*)d_in[9];
    const float* fcW1 = (const float*)d_in[10], *fcb1 = (const float*)d_in[11];
    const float* fcW2 = (const float*)d_in[12], *fcb2 = (const float*)d_in[13];
    const float* g1 = (const float*)d_in[14], *be1 = (const float*)d_in[15];
    const float* g2 = (const float*)d_in[16], *be2 = (const float*)d_in[17];
    const float* g3 = (const float*)d_in[18], *be3 = (const float*)d_in[19];
    float* out = (float*)d_out;

    const int* srcp = ei;
    const int* dstp = ei + NE;

    char* ws = (char*)d_ws;
    size_t off = 0;
    auto take = [&](size_t bytes) -> char* {
        char* p = ws + off;
        off += (bytes + 255) & ~(size_t)255;
        return p;
    };
    float* bufA    = (float*)take((size_t)NN * FD * 4);        // y1, then y3
    float* bufB    = (float*)take((size_t)NN * FD * 4);        // y2
    uint2* slots   = (uint2*)take((size_t)NN * CAP * 8);       // 25.6 MB
    float* affine  = (float*)take((size_t)3 * 2 * FD * 4);
    float* partial = (float*)take((size_t)NBLK * 128 * 4);     // 1.6 MB, reused
    size_t zero_base = off;
    int*   cursor  = (int*)  take((size_t)NN * 4);             // becomes deg
    size_t zero_bytes = off - zero_base;
    (void)ws_size; (void)n_in; (void)in_sizes; (void)out_size;

    hipMemsetAsync(ws + zero_base, 0, zero_bytes, stream);

    build_slots_kernel<<<(NE + 255) / 256, 256, 0, stream>>>(srcp, dstp, ew,
                                                             cursor, slots);

    float* af1 = affine + 0 * 128;
    float* af2 = affine + 1 * 128;
    float* af3 = affine + 2 * 128;

    agg_layer_kernel<<<NBLK, 256, 0, stream>>>(x, cursor, slots,
                                               nullptr, W1, b1, bufA, partial, 1);
    redfin_kernel<<<64, 256, 0, stream>>>(partial, g1, be1, af1);
    agg_layer_kernel<<<NBLK, 256, 0, stream>>>(bufA, cursor, slots,
                                               af1, W2, b2, bufB, partial, 1);
    redfin_kernel<<<64, 256, 0, stream>>>(partial, g2, be2, af2);
    agg_layer_kernel<<<NBLK, 256, 0, stream>>>(bufB, cursor, slots,
                                               af2, W3, b3, bufA, partial, 0);
    redfin_kernel<<<64, 256, 0, stream>>>(partial, g3, be3, af3);
    pool_head_kernel<<<NG, 256, 0, stream>>>(bufA, batch, af3,
                                             fcW1, fcb1, fcW2, fcb2, out);
}

// Round 9
// 287.847 us; speedup vs baseline: 1.1343x; 1.1343x over previous
//
#include <hip/hip_runtime.h>
#include <hip/hip_bf16.h>

// GIN GNN forward, R9 = R7 structure (best: 292us) + data-format shrink:
// - slot entry 4B: (src<<16)|bf16(w)  -> slot row 256B (was 512B), one
//   shuffle per edge (was two).
// - feature buffers bf16 (rows 128B, was 256B): gather/self/write traffic
//   halved. agg was L2-miss-byte-bound (~83MB @ ~1.4TB/s = ~60us).
// - x converted f32->bf16 once (cvt kernel).

#define NN 50000
#define NE 800000
#define FD 64
#define NG 256
#define CAP 64            // slots per node == wave width; max degree ~42
#define BN_EPS 1e-5f

__device__ __forceinline__ float4 dec4(uint2 a) {
    float4 f;
    f.x = __uint_as_float(a.x << 16);
    f.y = __uint_as_float(a.x & 0xFFFF0000u);
    f.z = __uint_as_float(a.y << 16);
    f.w = __uint_as_float(a.y & 0xFFFF0000u);
    return f;
}
__device__ __forceinline__ unsigned rbf(float f) {   // f32 -> bf16 bits (RNE)
    unsigned u = __float_as_uint(f);
    return (u + 0x7FFFu + ((u >> 16) & 1u)) >> 16;
}
__device__ __forceinline__ uint2 enc4(float4 v) {
    uint2 o;
    o.x = rbf(v.x) | (rbf(v.y) << 16);
    o.y = rbf(v.z) | (rbf(v.w) << 16);
    return o;
}

// ---------------- slot-table build ----------------
__global__ __launch_bounds__(256) void build_slots_kernel(
    const int* __restrict__ src, const int* __restrict__ dst,
    const float* __restrict__ ew, int* __restrict__ cursor,
    unsigned* __restrict__ slots)
{
    int e = blockIdx.x * 256 + threadIdx.x;
    if (e < NE) {
        int d = dst[e];
        int pos = atomicAdd(&cursor[d], 1) & (CAP - 1);
        slots[(size_t)d * CAP + pos] =
            ((unsigned)src[e] << 16) | rbf(ew[e]);
    }
}

// ---------------- x -> bf16 ----------------
__global__ __launch_bounds__(256) void cvt_kernel(
    const float4* __restrict__ xin, uint2* __restrict__ xout)
{
    int i = blockIdx.x * 256 + threadIdx.x;   // NN*16 = 800000 exact
    xout[i] = enc4(xin[i]);
}

// ---------------- fused layer (R7 structure) ----------------
// 1 node per wave; lane = (g = edge group, l = feature quad).
// hin = af (.) (y[node] + sum_e w*y[src]) + cf * (1 + sum_e w)
// y = [relu]( hin @ W + b ), + bucketed BN stats of y.
__global__ __launch_bounds__(256) void agg_layer_kernel(
    const uint2* __restrict__ h, const int* __restrict__ deg,
    const unsigned* __restrict__ slots, const float* __restrict__ affine,
    const float* __restrict__ W, const float* __restrict__ b,
    uint2* __restrict__ y, float* __restrict__ buckets, int relu_flag)
{
    __shared__ float Ws[FD * FD];       // 16 KB
    __shared__ float ps1[4][FD];
    __shared__ float ps2[4][FD];
    int tid  = threadIdx.x;
    int wave = tid >> 6, lane = tid & 63;
    int g = lane >> 4, l = lane & 15;
    int node = blockIdx.x * 4 + wave;   // 12500 * 4 == NN exact

    // stage W into LDS (coalesced float4)
    {
        float4* Wv = (float4*)Ws;
        const float4* Wg = (const float4*)W;
        #pragma unroll
        for (int i = 0; i < 4; i++) Wv[tid + 256 * i] = Wg[tid + 256 * i];
    }

    // slot row register-resident: lane i holds entry i (4B each)
    unsigned ms = slots[(size_t)node * CAP + lane];
    int dg = deg[node];                 // wave-uniform
    float4 self = dec4(h[(size_t)node * 16 + l]);
    if (dg > CAP) dg = CAP;

    __syncthreads();

    float4 acc = make_float4(0.f, 0.f, 0.f, 0.f);
    float wsum = 0.f;
    int nIter = (dg + 7) >> 3;          // WAVE-UNIFORM trip count
    for (int i = 0; i < nIter; i++) {
        int e0 = 8 * i + g;
        int e1 = e0 + 4;
        int ee0 = (e0 < dg) ? e0 : 0;   // clamp to valid lane
        int ee1 = (e1 < dg) ? e1 : 0;
        unsigned m0 = (unsigned)__shfl((int)ms, ee0, 64);
        unsigned m1 = (unsigned)__shfl((int)ms, ee1, 64);
        float w0 = __uint_as_float((m0 & 0xFFFFu) << 16);
        float w1 = __uint_as_float((m1 & 0xFFFFu) << 16);
        w0 = (e0 < dg) ? w0 : 0.f;      // mask invalid entries
        w1 = (e1 < dg) ? w1 : 0.f;
        float4 v0 = dec4(h[(size_t)(m0 >> 16) * 16 + l]);
        float4 v1 = dec4(h[(size_t)(m1 >> 16) * 16 + l]);
        wsum += w0 + w1;
        acc.x = fmaf(w0, v0.x, acc.x); acc.y = fmaf(w0, v0.y, acc.y);
        acc.z = fmaf(w0, v0.z, acc.z); acc.w = fmaf(w0, v0.w, acc.w);
        acc.x = fmaf(w1, v1.x, acc.x); acc.y = fmaf(w1, v1.y, acc.y);
        acc.z = fmaf(w1, v1.z, acc.z); acc.w = fmaf(w1, v1.w, acc.w);
    }
    // reduce across the 4 edge groups -> replicated in all lanes
    acc.x += __shfl_xor(acc.x, 16, 64); acc.y += __shfl_xor(acc.y, 16, 64);
    acc.z += __shfl_xor(acc.z, 16, 64); acc.w += __shfl_xor(acc.w, 16, 64);
    wsum  += __shfl_xor(wsum, 16, 64);
    acc.x += __shfl_xor(acc.x, 32, 64); acc.y += __shfl_xor(acc.y, 32, 64);
    acc.z += __shfl_xor(acc.z, 32, 64); acc.w += __shfl_xor(acc.w, 32, 64);
    wsum  += __shfl_xor(wsum, 32, 64);

    float4 raw;
    raw.x = self.x + acc.x; raw.y = self.y + acc.y;
    raw.z = self.z + acc.z; raw.w = self.w + acc.w;

    float4 af = make_float4(1.f, 1.f, 1.f, 1.f);
    float4 cf = make_float4(0.f, 0.f, 0.f, 0.f);
    if (affine) {
        af = ((const float4*)affine)[l];
        cf = ((const float4*)(affine + FD))[l];
    }
    float sw = 1.0f + wsum;
    float4 hin;
    hin.x = fmaf(af.x, raw.x, cf.x * sw);
    hin.y = fmaf(af.y, raw.y, cf.y * sw);
    hin.z = fmaf(af.z, raw.z, cf.z * sw);
    hin.w = fmaf(af.w, raw.w, cf.w * sw);

    // matvec: group g covers k in [16g, 16g+16); W rows from LDS
    const float4* __restrict__ WsV = (const float4*)Ws;
    float4 yp = make_float4(0.f, 0.f, 0.f, 0.f);
    #pragma unroll
    for (int kk = 0; kk < 4; kk++) {
        int srcl = 4 * g + kk;           // lane holding features 4*srcl..+3
        float a0 = __shfl(hin.x, srcl, 64);
        float a1 = __shfl(hin.y, srcl, 64);
        float a2 = __shfl(hin.z, srcl, 64);
        float a3 = __shfl(hin.w, srcl, 64);
        int k0 = 16 * g + 4 * kk;
        float4 w0 = WsV[(k0 + 0) * 16 + l];
        float4 w1 = WsV[(k0 + 1) * 16 + l];
        float4 w2 = WsV[(k0 + 2) * 16 + l];
        float4 w3 = WsV[(k0 + 3) * 16 + l];
        yp.x = fmaf(a0, w0.x, yp.x); yp.y = fmaf(a0, w0.y, yp.y);
        yp.z = fmaf(a0, w0.z, yp.z); yp.w = fmaf(a0, w0.w, yp.w);
        yp.x = fmaf(a1, w1.x, yp.x); yp.y = fmaf(a1, w1.y, yp.y);
        yp.z = fmaf(a1, w1.z, yp.z); yp.w = fmaf(a1, w1.w, yp.w);
        yp.x = fmaf(a2, w2.x, yp.x); yp.y = fmaf(a2, w2.y, yp.y);
        yp.z = fmaf(a2, w2.z, yp.z); yp.w = fmaf(a2, w2.w, yp.w);
        yp.x = fmaf(a3, w3.x, yp.x); yp.y = fmaf(a3, w3.y, yp.y);
        yp.z = fmaf(a3, w3.z, yp.z); yp.w = fmaf(a3, w3.w, yp.w);
    }
    yp.x += __shfl_xor(yp.x, 16, 64); yp.y += __shfl_xor(yp.y, 16, 64);
    yp.z += __shfl_xor(yp.z, 16, 64); yp.w += __shfl_xor(yp.w, 16, 64);
    yp.x += __shfl_xor(yp.x, 32, 64); yp.y += __shfl_xor(yp.y, 32, 64);
    yp.z += __shfl_xor(yp.z, 32, 64); yp.w += __shfl_xor(yp.w, 32, 64);

    float4 bias = ((const float4*)b)[l];
    float4 yv;
    yv.x = yp.x + bias.x; yv.y = yp.y + bias.y;
    yv.z = yp.z + bias.z; yv.w = yp.w + bias.w;
    if (relu_flag) {
        yv.x = fmaxf(yv.x, 0.f); yv.y = fmaxf(yv.y, 0.f);
        yv.z = fmaxf(yv.z, 0.f); yv.w = fmaxf(yv.w, 0.f);
    }
    if (g == 0) {
        y[(size_t)node * 16 + l] = enc4(yv);
        ((float4*)&ps1[wave][0])[l] = yv;
        float4 sq;
        sq.x = yv.x * yv.x; sq.y = yv.y * yv.y;
        sq.z = yv.z * yv.z; sq.w = yv.w * yv.w;
        ((float4*)&ps2[wave][0])[l] = sq;
    }
    __syncthreads();
    if (tid < FD) {
        float a = ps1[0][tid] + ps1[1][tid] + ps1[2][tid] + ps1[3][tid];
        float q = ps2[0][tid] + ps2[1][tid] + ps2[2][tid] + ps2[3][tid];
        float* bk = buckets + (blockIdx.x & 63) * 128;
        atomicAdd(&bk[tid], a);
        atomicAdd(&bk[FD + tid], q);
    }
}

// buckets -> BN affine coefficients (af, cf). 256 threads.
__global__ __launch_bounds__(256) void finalize_kernel(
    const float* __restrict__ buckets, const float* __restrict__ gamma,
    const float* __restrict__ beta, float* __restrict__ affine)
{
    __shared__ float part[4][2][FD];
    int tid = threadIdx.x;
    int f = tid & 63, q = tid >> 6;
    float S1 = 0.f, S2 = 0.f;
    #pragma unroll
    for (int i = 0; i < 16; i++) {
        int bkt = q * 16 + i;
        S1 += buckets[bkt * 128 + f];
        S2 += buckets[bkt * 128 + FD + f];
    }
    part[q][0][f] = S1;
    part[q][1][f] = S2;
    __syncthreads();
    if (tid < FD) {
        float s1 = part[0][0][tid] + part[1][0][tid] + part[2][0][tid] + part[3][0][tid];
        float s2 = part[0][1][tid] + part[1][1][tid] + part[2][1][tid] + part[3][1][tid];
        float mu  = s1 * (1.f / NN);
        float var = s2 * (1.f / NN) - mu * mu;
        float a = gamma[tid] * rsqrtf(var + BN_EPS);
        affine[tid]      = a;
        affine[FD + tid] = beta[tid] - mu * a;
    }
}

// ---------------- fused pool + head ----------------
__global__ __launch_bounds__(256) void pool_head_kernel(
    const uint2* __restrict__ y, const int* __restrict__ batch,
    const float* __restrict__ affine3,
    const float* __restrict__ fcW1, const float* __restrict__ fcb1,
    const float* __restrict__ fcW2, const float* __restrict__ fcb2,
    float* __restrict__ out)
{
    __shared__ float red[16][FD];
    __shared__ int bounds[2];
    int tid = threadIdx.x;
    int g = blockIdx.x;
    if (tid < 2) {
        int target = g + tid;           // lower_bound(batch, target)
        int lo = 0, hi = NN;
        while (lo < hi) {
            int mid = (lo + hi) >> 1;
            if (batch[mid] < target) lo = mid + 1; else hi = mid;
        }
        bounds[tid] = lo;
    }
    __syncthreads();
    int s = bounds[0], e = bounds[1];
    int l = tid & 15, r = tid >> 4;
    float4 acc = make_float4(0.f, 0.f, 0.f, 0.f);
    for (int n = s + r; n < e; n += 16) {
        float4 v = dec4(y[(size_t)n * 16 + l]);
        acc.x += v.x; acc.y += v.y; acc.z += v.z; acc.w += v.w;
    }
    ((float4*)&red[r][0])[l] = acc;
    __syncthreads();
    for (int off = 8; off > 0; off >>= 1) {
        if (r < off) {
            float4 a = ((float4*)&red[r][0])[l];
            float4 o = ((float4*)&red[r + off][0])[l];
            a.x += o.x; a.y += o.y; a.z += o.z; a.w += o.w;
            ((float4*)&red[r][0])[l] = a;
        }
        __syncthreads();
    }
    if (tid < 64) {                      // wave-uniform branch: shuffles safe
        float cnt = (float)(e - s);
        float p = red[0][tid];
        p = fmaf(affine3[tid], p, affine3[FD + tid] * cnt);  // BN3
        p = fmaxf(p, 0.f);
        float acc1 = fcb1[tid];
        #pragma unroll
        for (int k = 0; k < FD; k++) {
            float pk = __shfl(p, k, 64);
            acc1 = fmaf(pk, fcW1[k * FD + tid], acc1);
        }
        acc1 = fmaxf(acc1, 0.f);
        float prod = acc1 * fcW2[tid];
        #pragma unroll
        for (int off = 32; off > 0; off >>= 1)
            prod += __shfl_xor(prod, off, 64);
        if (tid == 0) out[g] = prod + fcb2[0];
    }
}

extern "C" void kernel_launch(void* const* d_in, const int* in_sizes, int n_in,
                              void* d_out, int out_size, void* d_ws, size_t ws_size,
                              hipStream_t stream) {
    const float* x     = (const float*)d_in[0];
    const int*   ei    = (const int*)d_in[1];
    const float* ew    = (const float*)d_in[2];
    const int*   batch = (const int*)d_in[3];
    const float* W1 = (const float*)d_in[4],  *b1 = (const float*)d_in[5];
    const float* W2 = (const float*)d_in[6],  *b2 = (const float*)d_in[7];
    const float* W3 = (const float*)d_in[8],  *b3 = (const float*)d_in[9];
    const float* fcW1 = (const float*)d_in[10], *fcb1 = (const float*)d_in[11];
    const float* fcW2 = (const float*)d_in[12], *fcb2 = (const float*)d_in[13];
    const float* g1 = (const float*)d_in[14], *be1 = (const float*)d_in[15];
    const float* g2 = (const float*)d_in[16], *be2 = (const float*)d_in[17];
    const float* g3 = (const float*)d_in[18], *be3 = (const float*)d_in[19];
    float* out = (float*)d_out;

    const int* srcp = ei;
    const int* dstp = ei + NE;

    char* ws = (char*)d_ws;
    size_t off = 0;
    auto take = [&](size_t bytes) -> char* {
        char* p = ws + off;
        off += (bytes + 255) & ~(size_t)255;
        return p;
    };
    uint2*    xbf   = (uint2*)   take((size_t)NN * FD * 2);    // 6.4 MB
    uint2*    bufA  = (uint2*)   take((size_t)NN * FD * 2);    // y1, then y3
    uint2*    bufB  = (uint2*)   take((size_t)NN * FD * 2);    // y2
    unsigned* slots = (unsigned*)take((size_t)NN * CAP * 4);   // 12.8 MB
    float*    affine= (float*)   take((size_t)3 * 2 * FD * 4);
    size_t zero_base = off;
    int*      cursor= (int*)     take((size_t)NN * 4);         // becomes deg
    float*    buckets=(float*)   take((size_t)3 * 64 * 128 * 4);
    size_t zero_bytes = off - zero_base;
    (void)ws_size; (void)n_in; (void)in_sizes; (void)out_size;

    hipMemsetAsync(ws + zero_base, 0, zero_bytes, stream);

    build_slots_kernel<<<(NE + 255) / 256, 256, 0, stream>>>(srcp, dstp, ew,
                                                             cursor, slots);
    cvt_kernel<<<(NN * 16) / 256, 256, 0, stream>>>((const float4*)x, xbf);

    const int gridA = NN / 4;   // 12500 blocks, 4 nodes (waves) each

    float* bk1 = buckets + 0 * 64 * 128;
    float* bk2 = buckets + 1 * 64 * 128;
    float* bk3 = buckets + 2 * 64 * 128;
    float* af1 = affine + 0 * 128;
    float* af2 = affine + 1 * 128;
    float* af3 = affine + 2 * 128;

    agg_layer_kernel<<<gridA, 256, 0, stream>>>(xbf, cursor, slots,
                                                nullptr, W1, b1, bufA, bk1, 1);
    finalize_kernel<<<1, 256, 0, stream>>>(bk1, g1, be1, af1);
    agg_layer_kernel<<<gridA, 256, 0, stream>>>(bufA, cursor, slots,
                                                af1, W2, b2, bufB, bk2, 1);
    finalize_kernel<<<1, 256, 0, stream>>>(bk2, g2, be2, af2);
    agg_layer_kernel<<<gridA, 256, 0, stream>>>(bufB, cursor, slots,
                                                af2, W3, b3, bufA, bk3, 0);
    finalize_kernel<<<1, 256, 0, stream>>>(bk3, g3, be3, af3);
    pool_head_kernel<<<NG, 256, 0, stream>>>(bufA, batch, af3,
                                             fcW1, fcb1, fcW2, fcb2, out);
}

// Round 10
// 265.254 us; speedup vs baseline: 1.2310x; 1.0852x over previous
//
#include <hip/hip_runtime.h>
#include <hip/hip_bf16.h>

// GIN GNN forward, R10 = R9 + two changes:
// 1) build_slots XCD-partitioned: part = blockIdx&7 (round-robin block->XCD
//    heuristic), each partition owns a disjoint 1.6MB slot slice + cursor
//    slice that fits its own L2 -> scattered writes/atomics merge locally
//    instead of cross-XCD line ping-pong (was 48MB WRITE). cvt fused in.
// 2) agg edge loop x4 wide (16 edges/iter): 4 independent gathers in
//    flight/lane (was 2) -> attacks gather MLP; nIter=1 for deg<=16.

#define NN 50000
#define NE 800000
#define FD 64
#define NG 256
#define CAP 64            // slots per node == wave width; max degree ~42
#define BN_EPS 1e-5f

#define NPART 8
#define PSIZE 6250        // nodes per XCD partition (49999/6250 == 7)
#define ECHUNK 2048       // edges per build block
#define NCHUNK ((NE + ECHUNK - 1) / ECHUNK)     // 391
#define NBUILD (NCHUNK * NPART)                 // 3128
#define NCVT   ((NN * 16) / 256)                // 3125

__device__ __forceinline__ float4 dec4(uint2 a) {
    float4 f;
    f.x = __uint_as_float(a.x << 16);
    f.y = __uint_as_float(a.x & 0xFFFF0000u);
    f.z = __uint_as_float(a.y << 16);
    f.w = __uint_as_float(a.y & 0xFFFF0000u);
    return f;
}
__device__ __forceinline__ unsigned rbf(float f) {   // f32 -> bf16 bits (RNE)
    unsigned u = __float_as_uint(f);
    return (u + 0x7FFFu + ((u >> 16) & 1u)) >> 16;
}
__device__ __forceinline__ uint2 enc4(float4 v) {
    uint2 o;
    o.x = rbf(v.x) | (rbf(v.y) << 16);
    o.y = rbf(v.z) | (rbf(v.w) << 16);
    return o;
}

// ---------------- fused: XCD-partitioned slot build + x->bf16 cvt ----------
__global__ __launch_bounds__(256) void build_cvt_kernel(
    const int* __restrict__ src, const int* __restrict__ dst,
    const float* __restrict__ ew, int* __restrict__ cursor,
    unsigned* __restrict__ slots,
    const float4* __restrict__ xin, uint2* __restrict__ xout)
{
    int bid = blockIdx.x;
    int tid = threadIdx.x;
    if (bid < NBUILD) {
        int part  = bid & 7;            // consecutive blocks -> different XCDs
        int chunk = bid >> 3;
        int base  = chunk * ECHUNK;
        #pragma unroll
        for (int i = 0; i < ECHUNK; i += 256) {
            int e = base + i + tid;
            if (e < NE) {
                int d = dst[e];
                if (d / PSIZE == part) {    // this XCD owns this dst slice
                    int pos = atomicAdd(&cursor[d], 1) & (CAP - 1);
                    slots[(size_t)d * CAP + pos] =
                        ((unsigned)src[e] << 16) | rbf(ew[e]);
                }
            }
        }
    } else {
        int i = (bid - NBUILD) * 256 + tid;   // NN*16 = 800000 exact
        xout[i] = enc4(xin[i]);
    }
}

// ---------------- fused layer ----------------
// 1 node per wave; lane = (g = edge group, l = feature quad).
// hin = af (.) (y[node] + sum_e w*y[src]) + cf * (1 + sum_e w)
// y = [relu]( hin @ W + b ), + bucketed BN stats of y.
__global__ __launch_bounds__(256) void agg_layer_kernel(
    const uint2* __restrict__ h, const int* __restrict__ deg,
    const unsigned* __restrict__ slots, const float* __restrict__ affine,
    const float* __restrict__ W, const float* __restrict__ b,
    uint2* __restrict__ y, float* __restrict__ buckets, int relu_flag)
{
    __shared__ float Ws[FD * FD];       // 16 KB
    __shared__ float ps1[4][FD];
    __shared__ float ps2[4][FD];
    int tid  = threadIdx.x;
    int wave = tid >> 6, lane = tid & 63;
    int g = lane >> 4, l = lane & 15;
    int node = blockIdx.x * 4 + wave;   // 12500 * 4 == NN exact

    // stage W into LDS (coalesced float4)
    {
        float4* Wv = (float4*)Ws;
        const float4* Wg = (const float4*)W;
        #pragma unroll
        for (int i = 0; i < 4; i++) Wv[tid + 256 * i] = Wg[tid + 256 * i];
    }

    // slot row register-resident: lane i holds entry i (4B each)
    unsigned ms = slots[(size_t)node * CAP + lane];
    int dg = deg[node];                 // wave-uniform
    float4 self = dec4(h[(size_t)node * 16 + l]);
    if (dg > CAP) dg = CAP;

    __syncthreads();

    float4 acc = make_float4(0.f, 0.f, 0.f, 0.f);
    float wsum = 0.f;
    int nIter = (dg + 15) >> 4;         // WAVE-UNIFORM; 16 edges per iter
    for (int i = 0; i < nIter; i++) {
        int e0 = 16 * i + g;
        int e1 = e0 + 4, e2 = e0 + 8, e3 = e0 + 12;
        int ee0 = (e0 < dg) ? e0 : 0;   // clamp to valid lane
        int ee1 = (e1 < dg) ? e1 : 0;
        int ee2 = (e2 < dg) ? e2 : 0;
        int ee3 = (e3 < dg) ? e3 : 0;
        unsigned m0 = (unsigned)__shfl((int)ms, ee0, 64);
        unsigned m1 = (unsigned)__shfl((int)ms, ee1, 64);
        unsigned m2 = (unsigned)__shfl((int)ms, ee2, 64);
        unsigned m3 = (unsigned)__shfl((int)ms, ee3, 64);
        float w0 = __uint_as_float((m0 & 0xFFFFu) << 16);
        float w1 = __uint_as_float((m1 & 0xFFFFu) << 16);
        float w2 = __uint_as_float((m2 & 0xFFFFu) << 16);
        float w3 = __uint_as_float((m3 & 0xFFFFu) << 16);
        w0 = (e0 < dg) ? w0 : 0.f;      // mask invalid entries
        w1 = (e1 < dg) ? w1 : 0.f;
        w2 = (e2 < dg) ? w2 : 0.f;
        w3 = (e3 < dg) ? w3 : 0.f;
        uint2 r0 = h[(size_t)(m0 >> 16) * 16 + l];   // 4 independent gathers
        uint2 r1 = h[(size_t)(m1 >> 16) * 16 + l];
        uint2 r2 = h[(size_t)(m2 >> 16) * 16 + l];
        uint2 r3 = h[(size_t)(m3 >> 16) * 16 + l];
        float4 v0 = dec4(r0), v1 = dec4(r1), v2 = dec4(r2), v3 = dec4(r3);
        wsum += (w0 + w1) + (w2 + w3);
        acc.x = fmaf(w0, v0.x, acc.x); acc.y = fmaf(w0, v0.y, acc.y);
        acc.z = fmaf(w0, v0.z, acc.z); acc.w = fmaf(w0, v0.w, acc.w);
        acc.x = fmaf(w1, v1.x, acc.x); acc.y = fmaf(w1, v1.y, acc.y);
        acc.z = fmaf(w1, v1.z, acc.z); acc.w = fmaf(w1, v1.w, acc.w);
        acc.x = fmaf(w2, v2.x, acc.x); acc.y = fmaf(w2, v2.y, acc.y);
        acc.z = fmaf(w2, v2.z, acc.z); acc.w = fmaf(w2, v2.w, acc.w);
        acc.x = fmaf(w3, v3.x, acc.x); acc.y = fmaf(w3, v3.y, acc.y);
        acc.z = fmaf(w3, v3.z, acc.z); acc.w = fmaf(w3, v3.w, acc.w);
    }
    // reduce across the 4 edge groups -> replicated in all lanes
    acc.x += __shfl_xor(acc.x, 16, 64); acc.y += __shfl_xor(acc.y, 16, 64);
    acc.z += __shfl_xor(acc.z, 16, 64); acc.w += __shfl_xor(acc.w, 16, 64);
    wsum  += __shfl_xor(wsum, 16, 64);
    acc.x += __shfl_xor(acc.x, 32, 64); acc.y += __shfl_xor(acc.y, 32, 64);
    acc.z += __shfl_xor(acc.z, 32, 64); acc.w += __shfl_xor(acc.w, 32, 64);
    wsum  += __shfl_xor(wsum, 32, 64);

    float4 raw;
    raw.x = self.x + acc.x; raw.y = self.y + acc.y;
    raw.z = self.z + acc.z; raw.w = self.w + acc.w;

    float4 af = make_float4(1.f, 1.f, 1.f, 1.f);
    float4 cf = make_float4(0.f, 0.f, 0.f, 0.f);
    if (affine) {
        af = ((const float4*)affine)[l];
        cf = ((const float4*)(affine + FD))[l];
    }
    float sw = 1.0f + wsum;
    float4 hin;
    hin.x = fmaf(af.x, raw.x, cf.x * sw);
    hin.y = fmaf(af.y, raw.y, cf.y * sw);
    hin.z = fmaf(af.z, raw.z, cf.z * sw);
    hin.w = fmaf(af.w, raw.w, cf.w * sw);

    // matvec: group g covers k in [16g, 16g+16); W rows from LDS
    const float4* __restrict__ WsV = (const float4*)Ws;
    float4 yp = make_float4(0.f, 0.f, 0.f, 0.f);
    #pragma unroll
    for (int kk = 0; kk < 4; kk++) {
        int srcl = 4 * g + kk;           // lane holding features 4*srcl..+3
        float a0 = __shfl(hin.x, srcl, 64);
        float a1 = __shfl(hin.y, srcl, 64);
        float a2 = __shfl(hin.z, srcl, 64);
        float a3 = __shfl(hin.w, srcl, 64);
        int k0 = 16 * g + 4 * kk;
        float4 w0 = WsV[(k0 + 0) * 16 + l];
        float4 w1 = WsV[(k0 + 1) * 16 + l];
        float4 w2 = WsV[(k0 + 2) * 16 + l];
        float4 w3 = WsV[(k0 + 3) * 16 + l];
        yp.x = fmaf(a0, w0.x, yp.x); yp.y = fmaf(a0, w0.y, yp.y);
        yp.z = fmaf(a0, w0.z, yp.z); yp.w = fmaf(a0, w0.w, yp.w);
        yp.x = fmaf(a1, w1.x, yp.x); yp.y = fmaf(a1, w1.y, yp.y);
        yp.z = fmaf(a1, w1.z, yp.z); yp.w = fmaf(a1, w1.w, yp.w);
        yp.x = fmaf(a2, w2.x, yp.x); yp.y = fmaf(a2, w2.y, yp.y);
        yp.z = fmaf(a2, w2.z, yp.z); yp.w = fmaf(a2, w2.w, yp.w);
        yp.x = fmaf(a3, w3.x, yp.x); yp.y = fmaf(a3, w3.y, yp.y);
        yp.z = fmaf(a3, w3.z, yp.z); yp.w = fmaf(a3, w3.w, yp.w);
    }
    yp.x += __shfl_xor(yp.x, 16, 64); yp.y += __shfl_xor(yp.y, 16, 64);
    yp.z += __shfl_xor(yp.z, 16, 64); yp.w += __shfl_xor(yp.w, 16, 64);
    yp.x += __shfl_xor(yp.x, 32, 64); yp.y += __shfl_xor(yp.y, 32, 64);
    yp.z += __shfl_xor(yp.z, 32, 64); yp.w += __shfl_xor(yp.w, 32, 64);

    float4 bias = ((const float4*)b)[l];
    float4 yv;
    yv.x = yp.x + bias.x; yv.y = yp.y + bias.y;
    yv.z = yp.z + bias.z; yv.w = yp.w + bias.w;
    if (relu_flag) {
        yv.x = fmaxf(yv.x, 0.f); yv.y = fmaxf(yv.y, 0.f);
        yv.z = fmaxf(yv.z, 0.f); yv.w = fmaxf(yv.w, 0.f);
    }
    if (g == 0) {
        y[(size_t)node * 16 + l] = enc4(yv);
        ((float4*)&ps1[wave][0])[l] = yv;
        float4 sq;
        sq.x = yv.x * yv.x; sq.y = yv.y * yv.y;
        sq.z = yv.z * yv.z; sq.w = yv.w * yv.w;
        ((float4*)&ps2[wave][0])[l] = sq;
    }
    __syncthreads();
    if (tid < FD) {
        float a = ps1[0][tid] + ps1[1][tid] + ps1[2][tid] + ps1[3][tid];
        float q = ps2[0][tid] + ps2[1][tid] + ps2[2][tid] + ps2[3][tid];
        float* bk = buckets + (blockIdx.x & 63) * 128;
        atomicAdd(&bk[tid], a);
        atomicAdd(&bk[FD + tid], q);
    }
}

// buckets -> BN affine coefficients (af, cf). 256 threads.
__global__ __launch_bounds__(256) void finalize_kernel(
    const float* __restrict__ buckets, const float* __restrict__ gamma,
    const float* __restrict__ beta, float* __restrict__ affine)
{
    __shared__ float part[4][2][FD];
    int tid = threadIdx.x;
    int f = tid & 63, q = tid >> 6;
    float S1 = 0.f, S2 = 0.f;
    #pragma unroll
    for (int i = 0; i < 16; i++) {
        int bkt = q * 16 + i;
        S1 += buckets[bkt * 128 + f];
        S2 += buckets[bkt * 128 + FD + f];
    }
    part[q][0][f] = S1;
    part[q][1][f] = S2;
    __syncthreads();
    if (tid < FD) {
        float s1 = part[0][0][tid] + part[1][0][tid] + part[2][0][tid] + part[3][0][tid];
        float s2 = part[0][1][tid] + part[1][1][tid] + part[2][1][tid] + part[3][1][tid];
        float mu  = s1 * (1.f / NN);
        float var = s2 * (1.f / NN) - mu * mu;
        float a = gamma[tid] * rsqrtf(var + BN_EPS);
        affine[tid]      = a;
        affine[FD + tid] = beta[tid] - mu * a;
    }
}

// ---------------- fused pool + head ----------------
__global__ __launch_bounds__(256) void pool_head_kernel(
    const uint2* __restrict__ y, const int* __restrict__ batch,
    const float* __restrict__ affine3,
    const float* __restrict__ fcW1, const float* __restrict__ fcb1,
    const float* __restrict__ fcW2, const float* __restrict__ fcb2,
    float* __restrict__ out)
{
    __shared__ float red[16][FD];
    __shared__ int bounds[2];
    int tid = threadIdx.x;
    int g = blockIdx.x;
    if (tid < 2) {
        int target = g + tid;           // lower_bound(batch, target)
        int lo = 0, hi = NN;
        while (lo < hi) {
            int mid = (lo + hi) >> 1;
            if (batch[mid] < target) lo = mid + 1; else hi = mid;
        }
        bounds[tid] = lo;
    }
    __syncthreads();
    int s = bounds[0], e = bounds[1];
    int l = tid & 15, r = tid >> 4;
    float4 acc = make_float4(0.f, 0.f, 0.f, 0.f);
    for (int n = s + r; n < e; n += 16) {
        float4 v = dec4(y[(size_t)n * 16 + l]);
        acc.x += v.x; acc.y += v.y; acc.z += v.z; acc.w += v.w;
    }
    ((float4*)&red[r][0])[l] = acc;
    __syncthreads();
    for (int off = 8; off > 0; off >>= 1) {
        if (r < off) {
            float4 a = ((float4*)&red[r][0])[l];
            float4 o = ((float4*)&red[r + off][0])[l];
            a.x += o.x; a.y += o.y; a.z += o.z; a.w += o.w;
            ((float4*)&red[r][0])[l] = a;
        }
        __syncthreads();
    }
    if (tid < 64) {                      // wave-uniform branch: shuffles safe
        float cnt = (float)(e - s);
        float p = red[0][tid];
        p = fmaf(affine3[tid], p, affine3[FD + tid] * cnt);  // BN3
        p = fmaxf(p, 0.f);
        float acc1 = fcb1[tid];
        #pragma unroll
        for (int k = 0; k < FD; k++) {
            float pk = __shfl(p, k, 64);
            acc1 = fmaf(pk, fcW1[k * FD + tid], acc1);
        }
        acc1 = fmaxf(acc1, 0.f);
        float prod = acc1 * fcW2[tid];
        #pragma unroll
        for (int off = 32; off > 0; off >>= 1)
            prod += __shfl_xor(prod, off, 64);
        if (tid == 0) out[g] = prod + fcb2[0];
    }
}

extern "C" void kernel_launch(void* const* d_in, const int* in_sizes, int n_in,
                              void* d_out, int out_size, void* d_ws, size_t ws_size,
                              hipStream_t stream) {
    const float* x     = (const float*)d_in[0];
    const int*   ei    = (const int*)d_in[1];
    const float* ew    = (const float*)d_in[2];
    const int*   batch = (const int*)d_in[3];
    const float* W1 = (const float*)d_in[4],  *b1 = (const float*)d_in[5];
    const float* W2 = (const float*)d_in[6],  *b2 = (const float*)d_in[7];
    const float* W3 = (const float*)d_in[8],  *b3 = (const float*)d_in[9];
    const float* fcW1 = (const float*)d_in[10], *fcb1 = (const float*)d_in[11];
    const float* fcW2 = (const float*)d_in[12], *fcb2 = (const float*)d_in[13];
    const float* g1 = (const float*)d_in[14], *be1 = (const float*)d_in[15];
    const float* g2 = (const float*)d_in[16], *be2 = (const float*)d_in[17];
    const float* g3 = (const float*)d_in[18], *be3 = (const float*)d_in[19];
    float* out = (float*)d_out;

    const int* srcp = ei;
    const int* dstp = ei + NE;

    char* ws = (char*)d_ws;
    size_t off = 0;
    auto take = [&](size_t bytes) -> char* {
        char* p = ws + off;
        off += (bytes + 255) & ~(size_t)255;
        return p;
    };
    uint2*    xbf   = (uint2*)   take((size_t)NN * FD * 2);    // 6.4 MB
    uint2*    bufA  = (uint2*)   take((size_t)NN * FD * 2);    // y1, then y3
    uint2*    bufB  = (uint2*)   take((size_t)NN * FD * 2);    // y2
    unsigned* slots = (unsigned*)take((size_t)NN * CAP * 4);   // 12.8 MB
    float*    affine= (float*)   take((size_t)3 * 2 * FD * 4);
    size_t zero_base = off;
    int*      cursor= (int*)     take((size_t)NN * 4);         // becomes deg
    float*    buckets=(float*)   take((size_t)3 * 64 * 128 * 4);
    size_t zero_bytes = off - zero_base;
    (void)ws_size; (void)n_in; (void)in_sizes; (void)out_size;

    hipMemsetAsync(ws + zero_base, 0, zero_bytes, stream);

    build_cvt_kernel<<<NBUILD + NCVT, 256, 0, stream>>>(srcp, dstp, ew,
                                                        cursor, slots,
                                                        (const float4*)x, xbf);

    const int gridA = NN / 4;   // 12500 blocks, 4 nodes (waves) each

    float* bk1 = buckets + 0 * 64 * 128;
    float* bk2 = buckets + 1 * 64 * 128;
    float* bk3 = buckets + 2 * 64 * 128;
    float* af1 = affine + 0 * 128;
    float* af2 = affine + 1 * 128;
    float* af3 = affine + 2 * 128;

    agg_layer_kernel<<<gridA, 256, 0, stream>>>(xbf, cursor, slots,
                                                nullptr, W1, b1, bufA, bk1, 1);
    finalize_kernel<<<1, 256, 0, stream>>>(bk1, g1, be1, af1);
    agg_layer_kernel<<<gridA, 256, 0, stream>>>(bufA, cursor, slots,
                                                af1, W2, b2, bufB, bk2, 1);
    finalize_kernel<<<1, 256, 0, stream>>>(bk2, g2, be2, af2);
    agg_layer_kernel<<<gridA, 256, 0, stream>>>(bufB, cursor, slots,
                                                af2, W3, b3, bufA, bk3, 0);
    finalize_kernel<<<1, 256, 0, stream>>>(bk3, g3, be3, af3);
    pool_head_kernel<<<NG, 256, 0, stream>>>(bufA, batch, af3,
                                             fcW1, fcb1, fcW2, fcb2, out);
}